// Round 11
// baseline (444.027 us; speedup 1.0000x reference)
//
#include <hip/hip_runtime.h>

#define V 4096
#define H 256
#define O 512
#define B 64
#define T 512

typedef __attribute__((ext_vector_type(8))) short bf16x8;
typedef __attribute__((ext_vector_type(4))) float f32x4;
typedef __attribute__((ext_vector_type(2))) float f32x2;

__device__ __forceinline__ unsigned short f2bf(float f) {
    unsigned int u = __float_as_uint(f);
    u += 0x7fffu + ((u >> 16) & 1u);
    return (unsigned short)(u >> 16);
}
__device__ __forceinline__ float bf2f(unsigned short s) {
    return __uint_as_float(((unsigned int)s) << 16);
}

// DPP cross-lane adds (VALU pipe, zero DS cost)
__device__ __forceinline__ float dpp_xor1(float v) {
    int i = __float_as_int(v);
    return __int_as_float(__builtin_amdgcn_update_dpp(i, i, 0xB1, 0xf, 0xf, true)); // quad_perm[1,0,3,2]
}
__device__ __forceinline__ float dpp_xor2(float v) {
    int i = __float_as_int(v);
    return __int_as_float(__builtin_amdgcn_update_dpp(i, i, 0x4E, 0xf, 0xf, true)); // quad_perm[2,3,0,1]
}
__device__ __forceinline__ float dpp_ror4(float v) {
    int i = __float_as_int(v);
    return __int_as_float(__builtin_amdgcn_update_dpp(i, i, 0x124, 0xf, 0xf, true)); // row_ror:4
}
__device__ __forceinline__ float dpp_ror8(float v) {
    int i = __float_as_int(v);
    return __int_as_float(__builtin_amdgcn_update_dpp(i, i, 0x128, 0xf, 0xf, true)); // row_ror:8
}
// sum with lane^32 partner via v_permlane32_swap (VALU, no DS):
// y=x; swap(y,x): lanes<32 get partner in y (x intact); lanes>=32: x.high
// becomes x.low_orig and y.high keeps x.high_orig -> x+y is the pair-sum
// for every lane.
__device__ __forceinline__ float xor32_add(float x) {
    float y = x;
    asm("v_permlane32_swap_b32 %0, %1" : "+v"(y), "+v"(x));
    return x + y;
}

// ---------------------------------------------------------------------------
// K1a: transpose W_ih [H][V] -> WihT [V][H] (coalesced per-step gather rows).
// ---------------------------------------------------------------------------
__global__ __launch_bounds__(256) void k_transpose(const float* __restrict__ Wih,
                                                   float* __restrict__ WihT) {
    __shared__ float tile[64][65];
    const int bi = blockIdx.x & 3;
    const int bv = blockIdx.x >> 2;
    const int tx = threadIdx.x & 63, ty = threadIdx.x >> 6;
#pragma unroll
    for (int s = 0; s < 16; ++s) {
        int r = ty + 4 * s;
        tile[r][tx] = Wih[(size_t)(bi * 64 + r) * V + bv * 64 + tx];
    }
    __syncthreads();
#pragma unroll
    for (int s = 0; s < 16; ++s) {
        int r = ty + 4 * s;
        WihT[(size_t)(bv * 64 + r) * H + bi * 64 + tx] = tile[tx][r];
    }
}

// ---------------------------------------------------------------------------
// K1b: split W_fc into bf16 hi + bf16 lo (B-side stays 2-term for accuracy).
// ---------------------------------------------------------------------------
__global__ __launch_bounds__(256) void k_prep(const float* __restrict__ Wfc,
                                              unsigned short* __restrict__ hi,
                                              unsigned short* __restrict__ lo) {
    int i = blockIdx.x * 256 + threadIdx.x;
    float w = Wfc[i];
    unsigned short h = f2bf(w);
    hi[i] = h;
    lo[i] = f2bf(w - bf2f(h));
}

// ---------------------------------------------------------------------------
// K2: persistent RNN. 64 blocks x 1024 threads (16 waves/CU, 4/SIMD — doubles
// TLP vs R10's 2/SIMD to hide the DS-drain + DPP/trans + barrier latencies
// that profiling shows are ~half the step).
// Thread: kk = (lane&15)|((lane&32)>>1) in [0,32) — k-slice of 8 terms;
//         g = ((lane>>4)&1)|(wave<<1) in [0,32) — row-group of 8 rows.
// Weights: 8 rows x 4 f32x2 = 64 floats (fits 128-VGPR budget at 4 waves/EU
// -> chance of true arch-VGPR residency + v_pk_fma_f32 formation).
// Reduce over the 32-way k-split: xor1,xor2 (quad DPP) narrowing selects,
// ror4+ror8 (16-row DPP rotation orbit = k bits 2,3), lane^32 via
// v_permlane32_swap (k bit 4) — ZERO DS ops. LDS h-reads: 2 x b128/thread
// (32 wave-instr/CU, same DS load as R10). CHS=12 floats: 16B-aligned
// chunks, bank spread 4-way max.
// ---------------------------------------------------------------------------
#define CHS 12   // floats per 8-float k-chunk (8 data + 4 pad)

__global__ __launch_bounds__(1024) void k_rnn(
    const int* __restrict__ x, const float* __restrict__ WihT,
    const float* __restrict__ Whh, const float* __restrict__ b_ih,
    const float* __restrict__ b_hh,
    unsigned short* __restrict__ hs_hi) {
    __shared__ float hsm[2][32 * CHS];
    const int b = blockIdx.x;
    const int tid = threadIdx.x;
    const int lane = tid & 63;
    const int wave = tid >> 6;
    const int kk = (lane & 15) | ((lane & 32) >> 1);   // k-slice 0..31
    const int g = ((lane >> 4) & 1) | (wave << 1);     // row-group 0..31
    const int own_row = 8 * g + (kk & 7);              // row this lane finalizes
    const int k0 = 8 * kk;

    // W_hh rows 8g..8g+7, k in [k0, k0+8): 32 f32x2 = 64 regs
    f32x2 w2[8][4];
#pragma unroll
    for (int r = 0; r < 8; ++r) {
        const f32x2* wr = (const f32x2*)(Whh + (size_t)(8 * g + r) * H + k0);
#pragma unroll
        for (int j = 0; j < 4; ++j) w2[r][j] = wr[j];
    }

    if (tid < 32 * CHS) hsm[0][tid] = 0.0f;
    const float bias = b_ih[own_row] + b_hh[own_row];
    __syncthreads();

    const int bT = b * T;
    float xp_cur = WihT[(size_t)x[bT] * H + own_row];   // scalar base + row voffset
    int xnext = x[bT + 1];

    for (int t = 0; t < T; ++t) {
        float xp_next = WihT[(size_t)xnext * H + own_row];

        // 2 x ds_read_b128: this lane's 8-float k-slice of h
        const f32x4* hv = (const f32x4*)&hsm[t & 1][kk * CHS];
        f32x4 q0 = hv[0], q1 = hv[1];
        f32x2 h2[4] = {{q0[0], q0[1]}, {q0[2], q0[3]}, {q1[0], q1[1]}, {q1[2], q1[3]}};
        f32x2 a0 = {0,0}, a1 = {0,0}, a2 = {0,0}, a3 = {0,0};
        f32x2 a4 = {0,0}, a5 = {0,0}, a6 = {0,0}, a7 = {0,0};
#pragma unroll
        for (int j = 0; j < 4; ++j) {
            a0 += h2[j] * w2[0][j];
            a1 += h2[j] * w2[1][j];
            a2 += h2[j] * w2[2][j];
            a3 += h2[j] * w2[3][j];
            a4 += h2[j] * w2[4][j];
            a5 += h2[j] * w2[5][j];
            a6 += h2[j] * w2[6][j];
            a7 += h2[j] * w2[7][j];
        }
        float s0 = a0[0] + a0[1], s1 = a1[0] + a1[1];
        float s2 = a2[0] + a2[1], s3 = a3[0] + a3[1];
        float s4 = a4[0] + a4[1], s5 = a5[0] + a5[1];
        float s6 = a6[0] + a6[1], s7 = a7[0] + a7[1];
        // k-bit0: quad DPP; keep rows with r&1 == kk&1
        s0 += dpp_xor1(s0); s1 += dpp_xor1(s1); s2 += dpp_xor1(s2); s3 += dpp_xor1(s3);
        s4 += dpp_xor1(s4); s5 += dpp_xor1(s5); s6 += dpp_xor1(s6); s7 += dpp_xor1(s7);
        const bool b0 = kk & 1, b1 = kk & 2, b2 = kk & 4;
        float u0 = b0 ? s1 : s0;
        float u1 = b0 ? s3 : s2;
        float u2 = b0 ? s5 : s4;
        float u3 = b0 ? s7 : s6;
        // k-bit1: quad DPP; keep rows with r&2 == kk&2
        u0 += dpp_xor2(u0); u1 += dpp_xor2(u1); u2 += dpp_xor2(u2); u3 += dpp_xor2(u3);
        float v0 = b1 ? u1 : u0;       // row 8g + (kk&3)
        float v1 = b1 ? u3 : u2;       // row 8g + 4 + (kk&3)
        // k-bits 2,3: rotation orbit within the 16-lane DPP row
        v0 += dpp_ror4(v0); v1 += dpp_ror4(v1);
        v0 += dpp_ror8(v0); v1 += dpp_ror8(v1);
        // k-bit4: lane^32 via permlane32_swap (VALU)
        v0 = xor32_add(v0);
        v1 = xor32_add(v1);
        float own = b2 ? v1 : v0;      // full k-sum for own_row

        float pre = own + xp_cur + bias;
        float e = __expf(2.0f * pre);              // tanh = 1 - 2/(e^{2x}+1)
        float hval = 1.0f - 2.0f * __builtin_amdgcn_rcpf(e + 1.0f);

        // LDS write: one dup-lane per row (kk&24 == 8 -> kk-8 == row&7)
        if ((kk & 24) == 8)
            hsm[(t + 1) & 1][g * CHS + (kk & 7)] = hval;

        // bf16 convert (RNE) in one instr
        int hb;
        asm("v_cvt_pk_bf16_f32 %0, %1, %2" : "=v"(hb) : "v"(hval), "v"(0.0f));

        // relaxed barrier: LDS visibility only; globals stay in flight
        asm volatile("s_waitcnt lgkmcnt(0)" ::: "memory");
        __builtin_amdgcn_s_barrier();

        // post-barrier tail: global store by another dup-lane (kk < 8)
        if ((kk & 24) == 0)
            __builtin_nontemporal_store((unsigned short)hb,
                                        &hs_hi[(size_t)(bT + t) * H + own_row]);
        xp_cur = xp_next;
        int tnn = (t + 2 < T) ? t + 2 : T - 1;
        xnext = x[bT + tnn];                       // scalar prefetch, 1 step slack
    }
}

// ---------------------------------------------------------------------------
// K3: FC GEMM [32768,256] x [256,512], A = bf16 hs, B = W_fc hi+lo (2 MFMA).
// 128x128 tile, BK=64, 4 waves (2x2, 64x64 each), XOR-swizzled LDS.
// ---------------------------------------------------------------------------
__global__ __launch_bounds__(256, 2) void k_fc(
    const unsigned short* __restrict__ hs_hi,
    const unsigned short* __restrict__ wfc_hi, const unsigned short* __restrict__ wfc_lo,
    const float* __restrict__ b_fc, float* __restrict__ out) {
    __shared__ short sA[128 * 64], sBh[128 * 64], sBl[128 * 64];
    const int tid = threadIdx.x;
    const int bm = blockIdx.x >> 2, bn = blockIdx.x & 3;
    const int m0 = bm * 128, n0 = bn * 128;
    const int w = tid >> 6, lane = tid & 63;
    const int wm = w >> 1, wn = w & 1;
    const int l16 = lane & 15, g = lane >> 4;

    f32x4 acc[4][4];
#pragma unroll
    for (int a = 0; a < 4; ++a)
#pragma unroll
        for (int cc = 0; cc < 4; ++cc)
#pragma unroll
            for (int qq = 0; qq < 4; ++qq) acc[a][cc][qq] = 0.0f;

    for (int kt = 0; kt < 4; ++kt) {
        const int k0 = kt * 64;
#pragma unroll
        for (int s = 0; s < 4; ++s) {
            int cidx = tid + 256 * s;
            int r = cidx >> 3, slot = cidx & 7;
            int dst = r * 64 + ((slot ^ (r & 7)) << 3);
            size_t ga = (size_t)(m0 + r) * 256 + k0 + slot * 8;
            *(bf16x8*)&sA[dst] = *(const bf16x8*)&hs_hi[ga];
            size_t gb = (size_t)(n0 + r) * 256 + k0 + slot * 8;
            *(bf16x8*)&sBh[dst] = *(const bf16x8*)&wfc_hi[gb];
            *(bf16x8*)&sBl[dst] = *(const bf16x8*)&wfc_lo[gb];
        }
        __syncthreads();
#pragma unroll
        for (int kc = 0; kc < 2; ++kc) {
            bf16x8 ah[4], bh[4], bl[4];
            const int slot = kc * 4 + g;
#pragma unroll
            for (int mi = 0; mi < 4; ++mi) {
                int r = wm * 64 + mi * 16 + l16;
                int off = r * 64 + ((slot ^ (r & 7)) << 3);
                ah[mi] = *(const bf16x8*)&sA[off];
            }
#pragma unroll
            for (int ni = 0; ni < 4; ++ni) {
                int r = wn * 64 + ni * 16 + l16;
                int off = r * 64 + ((slot ^ (r & 7)) << 3);
                bh[ni] = *(const bf16x8*)&sBh[off];
                bl[ni] = *(const bf16x8*)&sBl[off];
            }
#pragma unroll
            for (int mi = 0; mi < 4; ++mi)
#pragma unroll
                for (int ni = 0; ni < 4; ++ni) {
                    acc[mi][ni] = __builtin_amdgcn_mfma_f32_16x16x32_bf16(
                        ah[mi], bh[ni], acc[mi][ni], 0, 0, 0);
                    acc[mi][ni] = __builtin_amdgcn_mfma_f32_16x16x32_bf16(
                        ah[mi], bl[ni], acc[mi][ni], 0, 0, 0);
                }
        }
        __syncthreads();
    }
#pragma unroll
    for (int ni = 0; ni < 4; ++ni) {
        int n = n0 + wn * 64 + ni * 16 + l16;
        float bfc = b_fc[n];
#pragma unroll
        for (int mi = 0; mi < 4; ++mi) {
#pragma unroll
            for (int qq = 0; qq < 4; ++qq) {
                int m = m0 + wm * 64 + mi * 16 + g * 4 + qq;
                out[(size_t)m * O + n] = acc[mi][ni][qq] + bfc;
            }
        }
    }
}

extern "C" void kernel_launch(void* const* d_in, const int* in_sizes, int n_in,
                              void* d_out, int out_size, void* d_ws, size_t ws_size,
                              hipStream_t stream) {
    (void)in_sizes; (void)n_in; (void)out_size; (void)ws_size;
    const int*   x    = (const int*)d_in[0];
    const float* Wih  = (const float*)d_in[1];
    const float* Whh  = (const float*)d_in[2];
    const float* bih  = (const float*)d_in[3];
    const float* bhh  = (const float*)d_in[4];
    const float* Wfc  = (const float*)d_in[5];
    const float* bfc  = (const float*)d_in[6];
    float* out = (float*)d_out;

    char* ws = (char*)d_ws;
    float*          WihT = (float*)ws;                                  // 4 MB
    unsigned short* wfch = (unsigned short*)(ws + 4194304);             // 256 KB
    unsigned short* wfcl = (unsigned short*)(ws + 4194304 + 262144);    // 256 KB
    unsigned short* hsh  = (unsigned short*)(ws + 4718592);             // 16 MB

    k_transpose<<<256, 256, 0, stream>>>(Wih, WihT);
    k_prep<<<512, 256, 0, stream>>>(Wfc, wfch, wfcl);
    k_rnn<<<64, 1024, 0, stream>>>(x, WihT, Whh, bih, bhh, hsh);
    k_fc<<<1024, 256, 0, stream>>>(hsh, wfch, wfcl, bfc, out);
}

// Round 12
// 344.185 us; speedup vs baseline: 1.2901x; 1.2901x over previous
//
#include <hip/hip_runtime.h>

#define V 4096
#define H 256
#define O 512
#define B 64
#define T 512

typedef __attribute__((ext_vector_type(8))) short bf16x8;
typedef __attribute__((ext_vector_type(4))) float f32x4;
typedef __attribute__((ext_vector_type(2))) float f32x2;

__device__ __forceinline__ unsigned short f2bf(float f) {
    unsigned int u = __float_as_uint(f);
    u += 0x7fffu + ((u >> 16) & 1u);   // round-to-nearest-even
    return (unsigned short)(u >> 16);
}
__device__ __forceinline__ float bf2f(unsigned short s) {
    return __uint_as_float(((unsigned int)s) << 16);
}

// DPP cross-lane adds (VALU pipe, zero DS cost)
__device__ __forceinline__ float dpp_xor1(float v) {
    int i = __float_as_int(v);
    return __int_as_float(__builtin_amdgcn_update_dpp(i, i, 0xB1, 0xf, 0xf, true)); // quad_perm[1,0,3,2]
}
__device__ __forceinline__ float dpp_xor2(float v) {
    int i = __float_as_int(v);
    return __int_as_float(__builtin_amdgcn_update_dpp(i, i, 0x4E, 0xf, 0xf, true)); // quad_perm[2,3,0,1]
}
__device__ __forceinline__ float dpp_ror8(float v) {
    // row_ror:8 — within each 16-lane row, lane c reads lane c^8
    int i = __float_as_int(v);
    return __int_as_float(__builtin_amdgcn_update_dpp(i, i, 0x128, 0xf, 0xf, true));
}

// ---------------------------------------------------------------------------
// K1a: transpose W_ih [H][V] -> WihT [V][H] (coalesced per-step gather rows).
// ---------------------------------------------------------------------------
__global__ __launch_bounds__(256) void k_transpose(const float* __restrict__ Wih,
                                                   float* __restrict__ WihT) {
    __shared__ float tile[64][65];
    const int bi = blockIdx.x & 3;
    const int bv = blockIdx.x >> 2;
    const int tx = threadIdx.x & 63, ty = threadIdx.x >> 6;
#pragma unroll
    for (int s = 0; s < 16; ++s) {
        int r = ty + 4 * s;
        tile[r][tx] = Wih[(size_t)(bi * 64 + r) * V + bv * 64 + tx];
    }
    __syncthreads();
#pragma unroll
    for (int s = 0; s < 16; ++s) {
        int r = ty + 4 * s;
        WihT[(size_t)(bv * 64 + r) * H + bi * 64 + tx] = tile[tx][r];
    }
}

// ---------------------------------------------------------------------------
// K1b: split W_fc into bf16 hi + bf16 lo for the 3-MFMA FC.
// ---------------------------------------------------------------------------
__global__ __launch_bounds__(256) void k_prep(const float* __restrict__ Wfc,
                                              unsigned short* __restrict__ hi,
                                              unsigned short* __restrict__ lo) {
    int i = blockIdx.x * 256 + threadIdx.x;
    float w = Wfc[i];
    unsigned short h = f2bf(w);
    hi[i] = h;
    lo[i] = f2bf(w - bf2f(h));
}

// ---------------------------------------------------------------------------
// K2: persistent RNN — exact best-measured configuration (R6, 305 µs):
// 64 blocks x 512 threads (2 waves/SIMD). Thread (g = tid>>4, c = tid&15):
// rows 8g..8g+7, k-16th c (16 terms). Relaxed barrier (lgkmcnt-only),
// nontemporal hi/lo stores, DPP xor1/xor2 + 2x ds_swizzle xor4 + ror8 reduce.
// Plateau note: 6 configs at 305-330 µs; instruction-mix changes null, both
// structural variants (R7 fewer LDS-reads/thread, R11 more waves) regress.
// Step ≈ 1450 cyc = DS drain (~380) + VALU issue (~460) + serial tail (~350)
// imperfectly overlapped under per-step barrier lockstep.
// ---------------------------------------------------------------------------
#define CH16 20   // chunk stride in floats (16 data + 4 pad)

__global__ __launch_bounds__(512)
__attribute__((amdgpu_waves_per_eu(2, 2)))
void k_rnn(
    const int* __restrict__ x, const float* __restrict__ WihT,
    const float* __restrict__ Whh, const float* __restrict__ b_ih,
    const float* __restrict__ b_hh,
    unsigned short* __restrict__ hs_hi, unsigned short* __restrict__ hs_lo) {
    __shared__ float hsm[2][16 * CH16];
    __shared__ int xs[T];
    const int b = blockIdx.x;
    const int tid = threadIdx.x;
    const int g = tid >> 4;        // row-group 0..31 (8 rows each)
    const int c = tid & 15;        // k-16th 0..15 (16 terms)
    const int cr = c & 7;          // row within group this lane finalizes
    const int row = 8 * g + cr;
    const int k0 = 16 * c;

    // W_hh rows 8g..8g+7, k in [k0, k0+16): 64 f32x2 = 128 regs
    f32x2 w2[8][8];
#pragma unroll
    for (int r = 0; r < 8; ++r) {
        const f32x2* wr = (const f32x2*)(Whh + (size_t)(8 * g + r) * H + k0);
#pragma unroll
        for (int q = 0; q < 8; ++q) w2[r][q] = wr[q];
    }
#pragma unroll
    for (int r = 0; r < 8; ++r)
#pragma unroll
        for (int q = 0; q < 8; ++q)
            asm volatile("" : "+v"(w2[r][q]));

    xs[tid] = x[b * T + tid];
    if (tid < 16 * CH16) hsm[0][tid] = 0.0f;
    const float bias = b_ih[row] + b_hh[row];
    __syncthreads();   // full barrier once (init visibility incl. globals)

    unsigned short* ph = hs_hi + (size_t)b * T * H + row;
    unsigned short* pl = hs_lo + (size_t)b * T * H + row;

    float xp_cur = WihT[(size_t)xs[0] * H + row];
    unsigned short h_prev = 0;     // c<8 lanes carry hi, c>=8 carry lo

    for (int t = 0; t < T; ++t) {
        // store h_{t-1}: nontemporal (don't thrash WihT in L2); drains async
        if (t > 0) {
            if (c < 8) __builtin_nontemporal_store(h_prev, &ph[(size_t)(t - 1) * H]);
            else       __builtin_nontemporal_store(h_prev, &pl[(size_t)(t - 1) * H]);
        }
        int tn = (t + 1 < T) ? t + 1 : t;
        float xp_next = WihT[(size_t)xs[tn] * H + row];

        // 4 x ds_read_b128: 16 h values for this lane's k-slice
        const f32x4* hv = (const f32x4*)&hsm[t & 1][c * CH16];
        f32x4 q0 = hv[0], q1 = hv[1], q2 = hv[2], q3 = hv[3];
        f32x2 h2[8] = {{q0[0], q0[1]}, {q0[2], q0[3]}, {q1[0], q1[1]}, {q1[2], q1[3]},
                       {q2[0], q2[1]}, {q2[2], q2[3]}, {q3[0], q3[1]}, {q3[2], q3[3]}};
        f32x2 a0 = {0,0}, a1 = {0,0}, a2 = {0,0}, a3 = {0,0};
        f32x2 a4 = {0,0}, a5 = {0,0}, a6 = {0,0}, a7 = {0,0};
#pragma unroll
        for (int q = 0; q < 8; ++q) {
            a0 += h2[q] * w2[0][q];
            a1 += h2[q] * w2[1][q];
            a2 += h2[q] * w2[2][q];
            a3 += h2[q] * w2[3][q];
            a4 += h2[q] * w2[4][q];
            a5 += h2[q] * w2[5][q];
            a6 += h2[q] * w2[6][q];
            a7 += h2[q] * w2[7][q];
        }
        float s0 = a0[0] + a0[1], s1 = a1[0] + a1[1];
        float s2 = a2[0] + a2[1], s3 = a3[0] + a3[1];
        float s4 = a4[0] + a4[1], s5 = a5[0] + a5[1];
        float s6 = a6[0] + a6[1], s7 = a7[0] + a7[1];
        // level 1 (k): DPP adds; keep rows with r&1 == c&1
        s0 += dpp_xor1(s0); s1 += dpp_xor1(s1); s2 += dpp_xor1(s2); s3 += dpp_xor1(s3);
        s4 += dpp_xor1(s4); s5 += dpp_xor1(s5); s6 += dpp_xor1(s6); s7 += dpp_xor1(s7);
        const bool b0 = c & 1, b1 = c & 2, b2 = c & 4;
        float u0 = b0 ? s1 : s0;
        float u1 = b0 ? s3 : s2;
        float u2 = b0 ? s5 : s4;
        float u3 = b0 ? s7 : s6;
        // level 2: DPP adds; keep rows with r&2 == c&2
        u0 += dpp_xor2(u0); u1 += dpp_xor2(u1); u2 += dpp_xor2(u2); u3 += dpp_xor2(u3);
        float v0 = b1 ? u1 : u0;
        float v1 = b1 ? u3 : u2;
        // level 4: ds_swizzle xor4 (2 DS ops); keep row with r&4 == c&4
        v0 += __int_as_float(__builtin_amdgcn_ds_swizzle(__float_as_int(v0), 0x101F));
        v1 += __int_as_float(__builtin_amdgcn_ds_swizzle(__float_as_int(v1), 0x101F));
        float own = b2 ? v1 : v0;      // row = c&7, k-half per bit3 of c
        // level 8: DPP row_ror:8 == xor8 within the 16-lane group (VALU)
        own += dpp_ror8(own);

        float pre = own + xp_cur + bias;
        float e = __expf(2.0f * pre);              // tanh = 1 - 2/(e^{2x}+1)
        float hval = 1.0f - 2.0f * __builtin_amdgcn_rcpf(e + 1.0f);

        if (c < 8)
            hsm[(t + 1) & 1][(row >> 4) * CH16 + (row & 15)] = hval;
        unsigned short hh = f2bf(hval);
        h_prev = (c < 8) ? hh : f2bf(hval - bf2f(hh));
        xp_cur = xp_next;

        // relaxed barrier: LDS visibility only; globals stay in flight
        asm volatile("s_waitcnt lgkmcnt(0)" ::: "memory");
        __builtin_amdgcn_s_barrier();
        asm volatile("" ::: "memory");
    }
    if (c < 8) ph[(size_t)(T - 1) * H] = h_prev;
    else       pl[(size_t)(T - 1) * H] = h_prev;
}

// ---------------------------------------------------------------------------
// K3: FC GEMM [32768,256] x [256,512] via 3-split bf16 MFMA.
// 128x128 tile, BK=64, 4 waves (2x2, 64x64 each), XOR-swizzled LDS.
// ---------------------------------------------------------------------------
__global__ __launch_bounds__(256, 2) void k_fc(
    const unsigned short* __restrict__ hs_hi, const unsigned short* __restrict__ hs_lo,
    const unsigned short* __restrict__ wfc_hi, const unsigned short* __restrict__ wfc_lo,
    const float* __restrict__ b_fc, float* __restrict__ out) {
    __shared__ short sAh[128 * 64], sAl[128 * 64], sBh[128 * 64], sBl[128 * 64];
    const int tid = threadIdx.x;
    const int bm = blockIdx.x >> 2, bn = blockIdx.x & 3;
    const int m0 = bm * 128, n0 = bn * 128;
    const int w = tid >> 6, lane = tid & 63;
    const int wm = w >> 1, wn = w & 1;
    const int l16 = lane & 15, g = lane >> 4;

    f32x4 acc[4][4];
#pragma unroll
    for (int a = 0; a < 4; ++a)
#pragma unroll
        for (int cc = 0; cc < 4; ++cc)
#pragma unroll
            for (int q = 0; q < 4; ++q) acc[a][cc][q] = 0.0f;

    for (int kt = 0; kt < 4; ++kt) {
        const int k0 = kt * 64;
#pragma unroll
        for (int s = 0; s < 4; ++s) {
            int cidx = tid + 256 * s;
            int r = cidx >> 3, slot = cidx & 7;
            int dst = r * 64 + ((slot ^ (r & 7)) << 3);
            size_t ga = (size_t)(m0 + r) * 256 + k0 + slot * 8;
            *(bf16x8*)&sAh[dst] = *(const bf16x8*)&hs_hi[ga];
            *(bf16x8*)&sAl[dst] = *(const bf16x8*)&hs_lo[ga];
            size_t gb = (size_t)(n0 + r) * 256 + k0 + slot * 8;
            *(bf16x8*)&sBh[dst] = *(const bf16x8*)&wfc_hi[gb];
            *(bf16x8*)&sBl[dst] = *(const bf16x8*)&wfc_lo[gb];
        }
        __syncthreads();
#pragma unroll
        for (int kc = 0; kc < 2; ++kc) {
            bf16x8 ah[4], al[4], bh[4], bl[4];
            const int slot = kc * 4 + g;
#pragma unroll
            for (int mi = 0; mi < 4; ++mi) {
                int r = wm * 64 + mi * 16 + l16;
                int off = r * 64 + ((slot ^ (r & 7)) << 3);
                ah[mi] = *(const bf16x8*)&sAh[off];
                al[mi] = *(const bf16x8*)&sAl[off];
            }
#pragma unroll
            for (int ni = 0; ni < 4; ++ni) {
                int r = wn * 64 + ni * 16 + l16;
                int off = r * 64 + ((slot ^ (r & 7)) << 3);
                bh[ni] = *(const bf16x8*)&sBh[off];
                bl[ni] = *(const bf16x8*)&sBl[off];
            }
#pragma unroll
            for (int mi = 0; mi < 4; ++mi)
#pragma unroll
                for (int ni = 0; ni < 4; ++ni) {
                    acc[mi][ni] = __builtin_amdgcn_mfma_f32_16x16x32_bf16(
                        ah[mi], bh[ni], acc[mi][ni], 0, 0, 0);
                    acc[mi][ni] = __builtin_amdgcn_mfma_f32_16x16x32_bf16(
                        ah[mi], bl[ni], acc[mi][ni], 0, 0, 0);
                    acc[mi][ni] = __builtin_amdgcn_mfma_f32_16x16x32_bf16(
                        al[mi], bh[ni], acc[mi][ni], 0, 0, 0);
                }
        }
        __syncthreads();
    }
#pragma unroll
    for (int ni = 0; ni < 4; ++ni) {
        int n = n0 + wn * 64 + ni * 16 + l16;
        float bfc = b_fc[n];
#pragma unroll
        for (int mi = 0; mi < 4; ++mi) {
#pragma unroll
            for (int q = 0; q < 4; ++q) {
                int m = m0 + wm * 64 + mi * 16 + g * 4 + q;
                out[(size_t)m * O + n] = acc[mi][ni][q] + bfc;
            }
        }
    }
}

extern "C" void kernel_launch(void* const* d_in, const int* in_sizes, int n_in,
                              void* d_out, int out_size, void* d_ws, size_t ws_size,
                              hipStream_t stream) {
    (void)in_sizes; (void)n_in; (void)out_size; (void)ws_size;
    const int*   x    = (const int*)d_in[0];
    const float* Wih  = (const float*)d_in[1];
    const float* Whh  = (const float*)d_in[2];
    const float* bih  = (const float*)d_in[3];
    const float* bhh  = (const float*)d_in[4];
    const float* Wfc  = (const float*)d_in[5];
    const float* bfc  = (const float*)d_in[6];
    float* out = (float*)d_out;

    char* ws = (char*)d_ws;
    float*          WihT = (float*)ws;                                  // 4 MB
    unsigned short* wfch = (unsigned short*)(ws + 4194304);             // 256 KB
    unsigned short* wfcl = (unsigned short*)(ws + 4194304 + 262144);    // 256 KB
    unsigned short* hsh  = (unsigned short*)(ws + 4718592);             // 16 MB
    unsigned short* hsl  = (unsigned short*)(ws + 4718592 + 16777216);  // 16 MB

    k_transpose<<<256, 256, 0, stream>>>(Wih, WihT);
    k_prep<<<512, 256, 0, stream>>>(Wfc, wfch, wfcl);
    k_rnn<<<64, 512, 0, stream>>>(x, WihT, Whh, bih, bhh, hsh, hsl);
    k_fc<<<1024, 256, 0, stream>>>(hsh, hsl, wfch, wfcl, bfc, out);
}